// Round 6
// baseline (149.538 us; speedup 1.0000x reference)
//
#include <hip/hip_runtime.h>

#define BATCH 4
#define HH 56
#define WW 56
#define CC 128
#define NHD 4
#define HD 32
#define KS 7
#define NB 3
#define HWSZ (HH * WW)        // 3136
#define RPBW 13
#define QKV_N 384
#define QKV_ELE ((size_t)BATCH * NHD * HWSZ * HD)   // 1,605,632 floats per tensor

// ---------------- Kernel 1: QKV GEMM ----------------
// x [12544,128] @ w_qkv[128,384] + b -> q/k/v each [B,NH,HW,HD], q pre-scaled.
// 64x128 tile per 128-thr block (2 waves), 8x8 micro-tile on an 8x8 lane grid:
// each LDS frag read is shared by 8 lanes (same-address broadcast, m136-free),
// residual aliasing exactly 2-way (free). FMA:LDS-byte ratio ~8x better than
// a 4x8 split-lane layout -> VALU-bound, not LDS-bound.
__global__ __launch_bounds__(128) void qkv_gemm(
    const float* __restrict__ x, const float* __restrict__ w,
    const float* __restrict__ bias,
    float* __restrict__ qb, float* __restrict__ kb, float* __restrict__ vb)
{
    __shared__ float As[32][68];    // [k][m], 64 rows + pad (stride 272 B, 16B-mult)
    __shared__ float Bs[32][132];   // [k][n], 128 cols + pad (stride 528 B)

    const int tid  = threadIdx.x;
    const int wv   = tid >> 6;          // 0..1
    const int lane = tid & 63;
    const int ty   = lane >> 3;         // 0..7 -> rows 8ty..8ty+7
    const int tx   = lane & 7;          // 0..7
    const int cg   = 8 * (wv * 8 + tx); // col group 0..120
    const int m0   = blockIdx.x * 64;
    const int n0   = blockIdx.y * 128;

    float acc[8][8];
    {
        const float4 b0 = *(const float4*)(bias + n0 + cg);
        const float4 b1 = *(const float4*)(bias + n0 + cg + 4);
        #pragma unroll
        for (int i = 0; i < 8; ++i) {
            acc[i][0] = b0.x; acc[i][1] = b0.y; acc[i][2] = b0.z; acc[i][3] = b0.w;
            acc[i][4] = b1.x; acc[i][5] = b1.y; acc[i][6] = b1.z; acc[i][7] = b1.w;
        }
    }

    for (int kc = 0; kc < 128; kc += 32) {
        // stage x^T: 64 rows x 8 k-quads = 512 float4 tasks
        #pragma unroll
        for (int t = tid; t < 512; t += 128) {
            const int row = t >> 3;
            const int k4  = t & 7;
            const float4 xv = *(const float4*)(x + (size_t)(m0 + row) * CC + kc + 4 * k4);
            As[4 * k4 + 0][row] = xv.x;
            As[4 * k4 + 1][row] = xv.y;
            As[4 * k4 + 2][row] = xv.z;
            As[4 * k4 + 3][row] = xv.w;
        }
        // stage w: 32 k x 32 n-quads = 1024 float4 tasks
        #pragma unroll
        for (int t = tid; t < 1024; t += 128) {
            const int kr = t >> 5;
            const int n4 = t & 31;
            *(float4*)&Bs[kr][4 * n4] =
                *(const float4*)(w + (size_t)(kc + kr) * QKV_N + n0 + 4 * n4);
        }
        __syncthreads();
        #pragma unroll
        for (int kk = 0; kk < 32; ++kk) {
            const float4 a0 = *(const float4*)&As[kk][8 * ty];
            const float4 a1 = *(const float4*)&As[kk][8 * ty + 4];
            const float4 b0 = *(const float4*)&Bs[kk][cg];
            const float4 b1 = *(const float4*)&Bs[kk][cg + 4];
            const float av[8] = {a0.x, a0.y, a0.z, a0.w, a1.x, a1.y, a1.z, a1.w};
            const float bv[8] = {b0.x, b0.y, b0.z, b0.w, b1.x, b1.y, b1.z, b1.w};
            #pragma unroll
            for (int i = 0; i < 8; ++i)
                #pragma unroll
                for (int j = 0; j < 8; ++j)
                    acc[i][j] = fmaf(av[i], bv[j], acc[i][j]);
        }
        __syncthreads();
    }

    // scatter into q/k/v [B,NH,HW,HD]; n-tile == tensor boundary so t uniform.
    // cg is a multiple of 8 -> an 8-col group never crosses a head boundary.
    const int t     = n0 >> 7;   // 0=q 1=k 2=v
    float* dst      = (t == 0) ? qb : (t == 1) ? kb : vb;
    const float scl = (t == 0) ? 0.17677669529663687f : 1.0f;  // 32^-0.5
    const int head  = cg >> 5;
    const int d     = cg & 31;
    const int b     = m0 / HWSZ;      // 64 | 3136 so tile never crosses b
    #pragma unroll
    for (int i = 0; i < 8; ++i) {
        const int ij = m0 - b * HWSZ + 8 * ty + i;
        float* p = dst + ((size_t)(b * NHD + head) * HWSZ + ij) * HD + d;
        *(float4*)p       = make_float4(acc[i][0] * scl, acc[i][1] * scl,
                                        acc[i][2] * scl, acc[i][3] * scl);
        *(float4*)(p + 4) = make_float4(acc[i][4] * scl, acc[i][5] * scl,
                                        acc[i][6] * scl, acc[i][7] * scl);
    }
}

// ---------------- Kernel 2: neighborhood attention (R3-verified) ----------------
// Block = 256 threads = 4 waves per (b, head, 8x8 query tile).
// Each query handled by a quad: lane sub=tid&3 owns 8 channels; quad-reduce
// via xor-shuffles. K+V halo staged in LDS (pos padded to 197).
__global__ __launch_bounds__(256) void natten_attn(
    const float* __restrict__ qb, const float* __restrict__ kb,
    const float* __restrict__ vb, const float* __restrict__ rpb,
    float* __restrict__ ob)
{
    __shared__ float4 Ks[8][197];   // [c][pos]
    __shared__ float4 Vs[8][197];
    __shared__ float rpbs[RPBW * RPBW];

    const int tid = threadIdx.x;
    const int qid = tid >> 2;       // 0..63 query within 8x8 tile
    const int sub = tid & 3;        // channel-quarter
    const int qi_l = qid >> 3;
    const int qj_l = qid & 7;
    const int ti = blockIdx.x / 7;
    const int tj = blockIdx.x % 7;
    const int head = blockIdx.y;
    const int b    = blockIdx.z;
    const int qi = ti * 8 + qi_l;
    const int qj = tj * 8 + qj_l;
    const int R0 = min(max(ti * 8 - NB, 0), HH - 14);
    const int C0 = min(max(tj * 8 - NB, 0), WW - 14);

    const size_t base = (size_t)(b * NHD + head) * HWSZ;

    if (tid < RPBW * RPBW) rpbs[tid] = rpb[head * (RPBW * RPBW) + tid];

    // stage K+V halo (8 lanes cover one pixel's 128 B -> coalesced)
    for (int idx = tid; idx < 1568; idx += 256) {
        const int pos = idx >> 3;
        const int c   = idx & 7;
        const int ri  = pos / 14;
        const int rj  = pos - ri * 14;
        const size_t g = (base + (size_t)(R0 + ri) * WW + (C0 + rj)) * HD;
        Ks[c][pos] = ((const float4*)(kb + g))[c];
        Vs[c][pos] = ((const float4*)(vb + g))[c];
    }

    // q fragment: my 8 channels (pre-scaled in qkv_gemm)
    const int c0 = sub * 2;
    const float4* qp = (const float4*)(qb + (base + (size_t)qi * WW + qj) * HD) + c0;
    const float4 q0 = qp[0];
    const float4 q1 = qp[1];

    const int si  = min(max(qi - NB, 0), HH - KS);
    const int sj  = min(max(qj - NB, 0), WW - KS);
    const int ri0 = si - R0;
    const int rj0 = sj - C0;
    const int oi  = si - qi + (KS - 1);
    const int oj  = sj - qj + (KS - 1);

    __syncthreads();

    // scores: partial dot over my 8 channels, quad-reduce via shuffles
    float s[49];
    #pragma unroll
    for (int pi = 0; pi < 7; ++pi) {
        const int rowoff = (ri0 + pi) * 14 + rj0;
        const int boff   = (oi + pi) * RPBW + oj;
        #pragma unroll
        for (int pj = 0; pj < 7; ++pj) {
            const int pos = rowoff + pj;
            const float4 k0 = Ks[c0][pos];
            const float4 k1 = Ks[c0 + 1][pos];
            float d = q0.x * k0.x + q0.y * k0.y + q0.z * k0.z + q0.w * k0.w
                    + q1.x * k1.x + q1.y * k1.y + q1.z * k1.z + q1.w * k1.w;
            d += __shfl_xor(d, 1, 64);
            d += __shfl_xor(d, 2, 64);
            s[pi * 7 + pj] = d + rpbs[boff + pj];
        }
    }

    // softmax (replicated across the quad)
    float m = s[0];
    #pragma unroll
    for (int p = 1; p < 49; ++p) m = fmaxf(m, s[p]);
    float l = 0.f;
    #pragma unroll
    for (int p = 0; p < 49; ++p) { s[p] = __expf(s[p] - m); l += s[p]; }
    const float inv = 1.f / l;

    // PV over my 8 channels
    float4 o0 = make_float4(0.f, 0.f, 0.f, 0.f);
    float4 o1 = make_float4(0.f, 0.f, 0.f, 0.f);
    #pragma unroll
    for (int pi = 0; pi < 7; ++pi) {
        const int rowoff = (ri0 + pi) * 14 + rj0;
        #pragma unroll
        for (int pj = 0; pj < 7; ++pj) {
            const int pos = rowoff + pj;
            const float wt = s[pi * 7 + pj];
            const float4 v0 = Vs[c0][pos];
            const float4 v1 = Vs[c0 + 1][pos];
            o0.x += wt * v0.x; o0.y += wt * v0.y; o0.z += wt * v0.z; o0.w += wt * v0.w;
            o1.x += wt * v1.x; o1.y += wt * v1.y; o1.z += wt * v1.z; o1.w += wt * v1.w;
        }
    }

    // write [B,H,W,NH*HD]; quad writes one pixel's 32-ch slice
    float* op = ob + ((size_t)b * HWSZ + (size_t)qi * WW + qj) * CC + head * HD + sub * 8;
    ((float4*)op)[0] = make_float4(o0.x * inv, o0.y * inv, o0.z * inv, o0.w * inv);
    ((float4*)op)[1] = make_float4(o1.x * inv, o1.y * inv, o1.z * inv, o1.w * inv);
}

// ---------------- Kernel 3: output projection ----------------
// a [12544,128] @ w_proj[128,128] + b_proj. Same 8x8-broadcast structure,
// 64x128 tile per 128-thr block.
__global__ __launch_bounds__(128) void proj_gemm(
    const float* __restrict__ a, const float* __restrict__ w,
    const float* __restrict__ bias, float* __restrict__ out)
{
    __shared__ float As[32][68];
    __shared__ float Bs[32][132];

    const int tid  = threadIdx.x;
    const int wv   = tid >> 6;
    const int lane = tid & 63;
    const int ty   = lane >> 3;
    const int tx   = lane & 7;
    const int cg   = 8 * (wv * 8 + tx);
    const int m0   = blockIdx.x * 64;

    float acc[8][8];
    {
        const float4 b0 = *(const float4*)(bias + cg);
        const float4 b1 = *(const float4*)(bias + cg + 4);
        #pragma unroll
        for (int i = 0; i < 8; ++i) {
            acc[i][0] = b0.x; acc[i][1] = b0.y; acc[i][2] = b0.z; acc[i][3] = b0.w;
            acc[i][4] = b1.x; acc[i][5] = b1.y; acc[i][6] = b1.z; acc[i][7] = b1.w;
        }
    }

    for (int kc = 0; kc < 128; kc += 32) {
        #pragma unroll
        for (int t = tid; t < 512; t += 128) {
            const int row = t >> 3;
            const int k4  = t & 7;
            const float4 xv = *(const float4*)(a + (size_t)(m0 + row) * CC + kc + 4 * k4);
            As[4 * k4 + 0][row] = xv.x;
            As[4 * k4 + 1][row] = xv.y;
            As[4 * k4 + 2][row] = xv.z;
            As[4 * k4 + 3][row] = xv.w;
        }
        #pragma unroll
        for (int t = tid; t < 1024; t += 128) {
            const int kr = t >> 5;
            const int n4 = t & 31;
            *(float4*)&Bs[kr][4 * n4] =
                *(const float4*)(w + (size_t)(kc + kr) * CC + 4 * n4);
        }
        __syncthreads();
        #pragma unroll
        for (int kk = 0; kk < 32; ++kk) {
            const float4 a0 = *(const float4*)&As[kk][8 * ty];
            const float4 a1 = *(const float4*)&As[kk][8 * ty + 4];
            const float4 b0 = *(const float4*)&Bs[kk][cg];
            const float4 b1 = *(const float4*)&Bs[kk][cg + 4];
            const float av[8] = {a0.x, a0.y, a0.z, a0.w, a1.x, a1.y, a1.z, a1.w};
            const float bv[8] = {b0.x, b0.y, b0.z, b0.w, b1.x, b1.y, b1.z, b1.w};
            #pragma unroll
            for (int i = 0; i < 8; ++i)
                #pragma unroll
                for (int j = 0; j < 8; ++j)
                    acc[i][j] = fmaf(av[i], bv[j], acc[i][j]);
        }
        __syncthreads();
    }

    #pragma unroll
    for (int i = 0; i < 8; ++i) {
        float* p = out + (size_t)(m0 + 8 * ty + i) * CC + cg;
        *(float4*)p       = make_float4(acc[i][0], acc[i][1], acc[i][2], acc[i][3]);
        *(float4*)(p + 4) = make_float4(acc[i][4], acc[i][5], acc[i][6], acc[i][7]);
    }
}

extern "C" void kernel_launch(void* const* d_in, const int* in_sizes, int n_in,
                              void* d_out, int out_size, void* d_ws, size_t ws_size,
                              hipStream_t stream) {
    const float* x      = (const float*)d_in[0];
    const float* w_qkv  = (const float*)d_in[1];
    const float* b_qkv  = (const float*)d_in[2];
    const float* rpb    = (const float*)d_in[3];
    const float* w_proj = (const float*)d_in[4];
    const float* b_proj = (const float*)d_in[5];
    float* out = (float*)d_out;

    float* ws  = (float*)d_ws;
    float* qbf = ws;
    float* kbf = ws + QKV_ELE;
    float* vbf = ws + 2 * QKV_ELE;
    float* obf = ws + 3 * QKV_ELE;

    qkv_gemm<<<dim3(196, 3), 128, 0, stream>>>(x, w_qkv, b_qkv, qbf, kbf, vbf);
    natten_attn<<<dim3(49, NHD, BATCH), 256, 0, stream>>>(qbf, kbf, vbf, rpb, obf);
    proj_gemm<<<196, 128, 0, stream>>>(obf, w_proj, b_proj, out);
}